// Round 2
// baseline (3545.396 us; speedup 1.0000x reference)
//
#include <hip/hip_runtime.h>

#define T_SEQ   1024
#define T_STEPS 1023
#define BATCH   128
#define DIM     256
#define HID     1024
#define VOUT    128
#define WGS     256
#define HSLOT   131072   // ushorts per t-slot: 8 slices x 16384
#define SLICE_E 16384    // h elems per slice per t (16 rows x 1024), frag-blocked [hk 32][lq 4][row 16][j 8]
#define XSLICE  4096     // x elems per slice per t (16 rows x 256),  frag-blocked [xk 8][lq][row][j]

typedef __attribute__((ext_vector_type(8))) short short8;
typedef __attribute__((ext_vector_type(4))) float floatx4;

// async global->LDS, 16B per lane (linear copy: LDS dest = uniform base + lane*16)
#define GLDS(gp, lp) __builtin_amdgcn_global_load_lds( \
    (const __attribute__((address_space(1))) unsigned int*)(gp), \
    (__attribute__((address_space(3))) unsigned int*)(lp), 16, 0, 0)

__device__ __forceinline__ unsigned short f2bf(float x) {
    union { float f; unsigned u; } v; v.f = x;
    unsigned r = v.u + 0x7FFFu + ((v.u >> 16) & 1u);   // RNE
    return (unsigned short)(r >> 16);
}
__device__ __forceinline__ float sigm(float x) { return 1.0f / (1.0f + __expf(-x)); }

// ---------------- prep kernels ----------------

// h-weights bf16, wave-fragment order: [cg 32][w 8][i2 32][lane 64][j 8]
// w = cw*4+kw, i2 = tile*8+hi. Element: gate col gc = cw*64+tile*16+(l&15),
// h-col = (kw*8+hi)*32 + (l>>4)*8 + j. W row R = (gc>>5)*H + cg*32 + (gc&31).
__global__ void pack_w(const float* __restrict__ Whh, unsigned short* __restrict__ Wph) {
    const size_t idx = (size_t)blockIdx.x * 256 + threadIdx.x;
    if (idx >= (size_t)32 * 8 * 32 * 64 * 8) return;   // 4,194,304
    const int j   = (int)(idx & 7);
    const int l   = (int)((idx >> 3) & 63);
    const int rest = (int)(idx >> 9);
    const int i2  = rest & 31;
    const int w   = (rest >> 5) & 7;
    const int cg  = rest >> 8;
    const int tile = i2 >> 3, hi = i2 & 7;
    const int cw = w >> 2, kw = w & 3;
    const int gc = cw * 64 + tile * 16 + (l & 15);
    const int R  = (gc >> 5) * HID + cg * 32 + (gc & 31);
    const int hcol = (kw * 8 + hi) * 32 + (l >> 4) * 8 + j;
    Wph[idx] = f2bf(Whh[(size_t)R * HID + hcol]);
}

// x-weights bf16: [cg 32][w 8][fi 8][lane 64][j 8], fi = tile*2+xi,
// x-col = (kw*2+xi)*32 + (l>>4)*8 + j
__global__ void pack_xw(const float* __restrict__ Wih, unsigned short* __restrict__ Xw) {
    const size_t idx = (size_t)blockIdx.x * 256 + threadIdx.x;
    if (idx >= (size_t)32 * 8 * 8 * 64 * 8) return;    // 1,048,576
    const int j   = (int)(idx & 7);
    const int l   = (int)((idx >> 3) & 63);
    const int rest = (int)(idx >> 9);
    const int fi  = rest & 7;
    const int w   = (rest >> 3) & 7;
    const int cg  = rest >> 6;
    const int tile = fi >> 1, xi = fi & 1;
    const int cw = w >> 2, kw = w & 3;
    const int gc = cw * 64 + tile * 16 + (l & 15);
    const int R  = (gc >> 5) * HID + cg * 32 + (gc & 31);
    const int xcol = (kw * 2 + xi) * 32 + (l >> 4) * 8 + j;
    Xw[idx] = f2bf(Wih[(size_t)R * DIM + xcol]);
}

// bias in natural (gate*H + hcol) order
__global__ void pack_bias(const float* __restrict__ bih, const float* __restrict__ bhh,
                          float* __restrict__ bc) {
    const int idx = blockIdx.x * 256 + threadIdx.x;
    if (idx < 4096) bc[idx] = bih[idx] + bhh[idx];
}

__global__ void pack_wout(const float* __restrict__ Wo, unsigned short* __restrict__ WoBf) {
    const int idx = blockIdx.x * 256 + threadIdx.x;
    if (idx < VOUT * HID) WoBf[idx] = f2bf(Wo[idx]);
}

// sequence [B, T, D] fp32 -> Xb [t][s8][xk 8][lq 4][row 16][j 8] bf16
__global__ void pack_x(const float* __restrict__ seq, unsigned short* __restrict__ Xb) {
    const size_t idx = (size_t)blockIdx.x * 256 + threadIdx.x;
    if (idx >= (size_t)T_STEPS * BATCH * DIM) return;
    const int j   = (int)(idx & 7);
    const int row = (int)((idx >> 3) & 15);
    const int lq  = (int)((idx >> 7) & 3);
    const int kk  = (int)((idx >> 9) & 7);
    const int s8  = (int)((idx >> 12) & 7);
    const int t   = (int)(idx >> 15);
    const int b = s8 * 16 + row;
    const int k = kk * 32 + lq * 8 + j;
    Xb[idx] = f2bf(seq[((size_t)b * T_SEQ + t) * DIM + k]);
}

__global__ void init_state(unsigned short* __restrict__ Hb, int* __restrict__ bar) {
    const int idx = blockIdx.x * 256 + threadIdx.x;
    if (idx < HSLOT) Hb[idx] = 0;          // t=0 slot zeros
    if (idx < 4096) bar[idx] = 0;          // per-WG flags
}

// ---------------- persistent recurrent kernel ----------------
// 256 WGs x 512 threads, 1 WG/CU. Slice s8 = wg&7 (16 batch rows) owned by 32 WGs
// (cg = wg>>3 -> h-cols [cg*32, cg*32+32)). Wave (cw,kw): 64 gate cols x 8 h-frags.
// h-weights in VGPR (128/wave), x-weights in LDS. x-partials for t+1 computed in
// the wait window; per-wave partial flag polling (8 producers each); h A-frags
// loaded per-lane direct to VGPR.
__global__ __launch_bounds__(512, 1) void lstm_persist(
    const unsigned short* __restrict__ Xb,
    unsigned short* __restrict__ Hblk,
    const unsigned short* __restrict__ Wph,
    const unsigned short* __restrict__ Xw,
    const float* __restrict__ bc,
    int* __restrict__ bar)
{
    __shared__ short8 xwl[64 * 64];   // 64 KB  x-weight frags [w*8+fi][lane]
    __shared__ float  gl[4][16][132]; // 33 KB  per-kw gate partials (padded)

    const int wg  = blockIdx.x;
    const int s8  = wg & 7;
    const int cg  = wg >> 3;
    const int tid = threadIdx.x;
    const int w   = tid >> 6;
    const int l   = tid & 63;
    const int lr  = l & 15;
    const int lq  = l >> 4;
    const int cw  = w >> 2;
    const int kw  = w & 3;
    const int cbase = cw * 64;
    const int lq4 = lq * 4;

    // stage x-weights (64 KB) once
    {
        const unsigned short* xsrc = Xw + (size_t)cg * 32768;
        #pragma unroll
        for (int i = 0; i < 8; ++i)
            GLDS(xsrc + i * 4096 + tid * 8, (unsigned short*)xwl + i * 4096 + tid * 8);
    }

    // h-weight fragments -> registers (held all steps): 32 x short8 = 128 VGPRs
    const short8* wpw = (const short8*)Wph + (size_t)(cg * 8 + w) * 32 * 64 + l;
    short8 bh[32];
    #pragma unroll
    for (int i = 0; i < 32; ++i) bh[i] = wpw[i * 64];

    // epilogue constants: tid = elq*128 + er*8 + ej -> cell (row er, h-col hc)
    const int er  = (tid >> 3) & 15;
    const int ej  = tid & 7;
    const int elq = tid >> 7;
    const int hc  = elq * 8 + ej;
    const float bi  = bc[0 * HID + cg * 32 + hc];
    const float bf_ = bc[1 * HID + cg * 32 + hc];
    const float bg  = bc[2 * HID + cg * 32 + hc];
    const float bo_ = bc[3 * HID + cg * 32 + hc];
    float creg = 0.f;

    __syncthreads();   // xwl ready

    // wave-local pointers
    const short8* xwv = xwl + (w * 8) * 64 + l;                          // B frags (x)
    const unsigned short* hb0 = Hblk + (size_t)s8 * SLICE_E + (size_t)(kw * 8) * 512 + (size_t)l * 8;
    const unsigned short* xa0 = Xb + (size_t)s8 * XSLICE + (size_t)(kw * 2) * 512 + (size_t)l * 8;
    int* flagp = &bar[s8 * 64 + kw * 8 + (l & 7)];

    // x-partials for t=0
    floatx4 acx0 = {0.f,0.f,0.f,0.f}, acx1 = acx0, acx2 = acx0, acx3 = acx0;
    #pragma unroll
    for (int xi = 0; xi < 2; ++xi) {
        short8 a = *(const short8*)(xa0 + xi * 512);
        acx0 = __builtin_amdgcn_mfma_f32_16x16x32_bf16(a, xwv[(0*2+xi)*64], acx0, 0,0,0);
        acx1 = __builtin_amdgcn_mfma_f32_16x16x32_bf16(a, xwv[(1*2+xi)*64], acx1, 0,0,0);
        acx2 = __builtin_amdgcn_mfma_f32_16x16x32_bf16(a, xwv[(2*2+xi)*64], acx2, 0,0,0);
        acx3 = __builtin_amdgcn_mfma_f32_16x16x32_bf16(a, xwv[(3*2+xi)*64], acx3, 0,0,0);
    }

    for (int t = 0; t < T_STEPS; ++t) {
        // ---- h phase: 8 per-lane dwordx4 loads + 32 MFMAs (critical path) ----
        {
            const unsigned short* hp = hb0 + (size_t)t * HSLOT;
            short8 ha[8];
            #pragma unroll
            for (int i = 0; i < 8; ++i) ha[i] = *(const short8*)(hp + i * 512);
            #pragma unroll
            for (int i = 0; i < 8; ++i) {
                acx0 = __builtin_amdgcn_mfma_f32_16x16x32_bf16(ha[i], bh[ 0 + i], acx0, 0,0,0);
                acx1 = __builtin_amdgcn_mfma_f32_16x16x32_bf16(ha[i], bh[ 8 + i], acx1, 0,0,0);
                acx2 = __builtin_amdgcn_mfma_f32_16x16x32_bf16(ha[i], bh[16 + i], acx2, 0,0,0);
                acx3 = __builtin_amdgcn_mfma_f32_16x16x32_bf16(ha[i], bh[24 + i], acx3, 0,0,0);
            }
        }

        // ---- stage gate partials (C/D: col=lane&15, row=lq*4+r) ----
        #pragma unroll
        for (int r = 0; r < 4; ++r) {
            gl[kw][lq4 + r][cbase      + lr] = acx0[r];
            gl[kw][lq4 + r][cbase + 16 + lr] = acx1[r];
            gl[kw][lq4 + r][cbase + 32 + lr] = acx2[r];
            gl[kw][lq4 + r][cbase + 48 + lr] = acx3[r];
        }
        __syncthreads();

        // ---- fused cell update: one cell per thread ----
        float gi = bi, gf = bf_, gg = bg, go = bo_;
        #pragma unroll
        for (int q = 0; q < 4; ++q) {
            gi += gl[q][er][ 0 + hc];
            gf += gl[q][er][32 + hc];
            gg += gl[q][er][64 + hc];
            go += gl[q][er][96 + hc];
        }
        const float iv = sigm(gi), fv = sigm(gf), ov = sigm(go);
        const float gv = tanhf(gg);
        creg = fv * creg + iv * gv;
        const unsigned hu = f2bf(ov * tanhf(creg));
        const unsigned up = (unsigned)__shfl_down((int)hu, 1);
        if ((tid & 1) == 0) {
            unsigned* hp = (unsigned*)(Hblk + (size_t)(t + 1) * HSLOT
                          + (size_t)s8 * SLICE_E + (size_t)cg * 512 + tid);
            __hip_atomic_store(hp, hu | (up << 16), __ATOMIC_RELAXED, __HIP_MEMORY_SCOPE_AGENT);
        }
        __syncthreads();   // drains all waves' h stores to IC

        if (t + 1 < T_STEPS) {
            // publish h(t+1)
            if (tid == 0)
                __hip_atomic_store(&bar[s8 * 64 + cg], t + 1,
                                   __ATOMIC_RELAXED, __HIP_MEMORY_SCOPE_AGENT);

            // ---- wait window: x-partials for t+1 (no recurrence dependency) ----
            const unsigned short* xp = xa0 + (size_t)(t + 1) * (BATCH * DIM);
            #pragma unroll
            for (int xi = 0; xi < 2; ++xi) {
                short8 a = *(const short8*)(xp + xi * 512);
                acx0 = (xi == 0) ? __builtin_amdgcn_mfma_f32_16x16x32_bf16(a, xwv[0*64], (floatx4){0.f,0.f,0.f,0.f}, 0,0,0)
                                 : __builtin_amdgcn_mfma_f32_16x16x32_bf16(a, xwv[1*64], acx0, 0,0,0);
                acx1 = (xi == 0) ? __builtin_amdgcn_mfma_f32_16x16x32_bf16(a, xwv[2*64], (floatx4){0.f,0.f,0.f,0.f}, 0,0,0)
                                 : __builtin_amdgcn_mfma_f32_16x16x32_bf16(a, xwv[3*64], acx1, 0,0,0);
                acx2 = (xi == 0) ? __builtin_amdgcn_mfma_f32_16x16x32_bf16(a, xwv[4*64], (floatx4){0.f,0.f,0.f,0.f}, 0,0,0)
                                 : __builtin_amdgcn_mfma_f32_16x16x32_bf16(a, xwv[5*64], acx2, 0,0,0);
                acx3 = (xi == 0) ? __builtin_amdgcn_mfma_f32_16x16x32_bf16(a, xwv[6*64], (floatx4){0.f,0.f,0.f,0.f}, 0,0,0)
                                 : __builtin_amdgcn_mfma_f32_16x16x32_bf16(a, xwv[7*64], acx3, 0,0,0);
            }

            // ---- per-wave poll: only this wave's 8 producers ----
            {
                const int need = t + 1;
                int bud = 1 << 22;
                while (true) {
                    const int f = __hip_atomic_load(flagp, __ATOMIC_RELAXED,
                                                    __HIP_MEMORY_SCOPE_AGENT);
                    if (__all(f >= need)) break;
                    if (--bud < 0) break;
                }
                __builtin_amdgcn_sched_barrier(0);
            }
        }
    }
}

// ---------------- deferred head: logits + log-softmax ----------------
__global__ __launch_bounds__(256, 2) void head_ls(
    const unsigned short* __restrict__ Hblk,
    const unsigned short* __restrict__ Wo,
    const float* __restrict__ bo,
    float* __restrict__ out)
{
    const int bg = blockIdx.x;    // slice 0..7
    const int t  = blockIdx.y;    // 0..1022
    const int tid = threadIdx.x;
    const int w  = tid >> 6;
    const int l  = tid & 63;
    const int lr = l & 15;
    const int lq = l >> 4;
    const int b0 = bg * 16;

    const short8* ap = (const short8*)(Hblk + (size_t)(t + 1) * HSLOT
                       + (size_t)bg * SLICE_E) + l;
    const unsigned short* bp0 = Wo + (size_t)(w * 32 + lr) * HID + lq * 8;
    const unsigned short* bp1 = Wo + (size_t)(w * 32 + 16 + lr) * HID + lq * 8;

    floatx4 a0 = {0.f, 0.f, 0.f, 0.f}, a1 = {0.f, 0.f, 0.f, 0.f};
    #pragma unroll 8
    for (int kk = 0; kk < 32; ++kk) {
        short8 a   = ap[kk * 64];
        short8 b0v = *(const short8*)(bp0 + kk * 32);
        short8 b1v = *(const short8*)(bp1 + kk * 32);
        a0 = __builtin_amdgcn_mfma_f32_16x16x32_bf16(a, b0v, a0, 0, 0, 0);
        a1 = __builtin_amdgcn_mfma_f32_16x16x32_bf16(a, b1v, a1, 0, 0, 0);
    }

    __shared__ float lg[16][132];
    #pragma unroll
    for (int r = 0; r < 4; ++r) {
        lg[lq * 4 + r][w * 32 + lr]      = a0[r] + bo[w * 32 + lr];
        lg[lq * 4 + r][w * 32 + 16 + lr] = a1[r] + bo[w * 32 + 16 + lr];
    }
    __syncthreads();

    const int row = tid >> 4;
    const int c   = tid & 15;
    float vals[8];
    float m = -1e30f;
    #pragma unroll
    for (int jv = 0; jv < 8; ++jv) { vals[jv] = lg[row][c + jv * 16]; m = fmaxf(m, vals[jv]); }
    #pragma unroll
    for (int d = 8; d >= 1; d >>= 1) m = fmaxf(m, __shfl_xor(m, d, 16));
    float ssum = 0.f;
    #pragma unroll
    for (int jv = 0; jv < 8; ++jv) ssum += __expf(vals[jv] - m);
    #pragma unroll
    for (int d = 8; d >= 1; d >>= 1) ssum += __shfl_xor(ssum, d, 16);
    const float lse = m + __logf(ssum);

    float* op = out + ((size_t)(b0 + row) * T_STEPS + t) * VOUT;
    #pragma unroll
    for (int jv = 0; jv < 8; ++jv) op[c + jv * 16] = vals[jv] - lse;
}

// ---------------- launcher ----------------
extern "C" void kernel_launch(void* const* d_in, const int* in_sizes, int n_in,
                              void* d_out, int out_size, void* d_ws, size_t ws_size,
                              hipStream_t stream) {
    const float* seq  = (const float*)d_in[0];
    const float* Wih  = (const float*)d_in[1];
    const float* Whh  = (const float*)d_in[2];
    const float* bih  = (const float*)d_in[3];
    const float* bhh  = (const float*)d_in[4];
    const float* Wout = (const float*)d_in[5];
    const float* bout = (const float*)d_in[6];
    float* out = (float*)d_out;

    char* p = (char*)d_ws;
    unsigned short* Wph  = (unsigned short*)p; p += (size_t)32 * 8 * 32 * 64 * 8 * 2;       // 8 MB
    unsigned short* Xw   = (unsigned short*)p; p += (size_t)32 * 8 * 8 * 64 * 8 * 2;        // 2 MB
    unsigned short* WoBf = (unsigned short*)p; p += (size_t)VOUT * HID * 2;                 // 256 KB
    float*          bc   = (float*)p;          p += (size_t)4096 * 4;                       // 16 KB
    int*            bar  = (int*)p;            p += (size_t)4096 * 4;                       // 16 KB
    unsigned short* Xb   = (unsigned short*)p; p += (size_t)T_STEPS * BATCH * DIM * 2;      // 67 MB
    unsigned short* Hblk = (unsigned short*)p; p += (size_t)(T_STEPS + 1) * HSLOT * 2;      // 268 MB

    pack_w    <<<16384, 256, 0, stream>>>(Whh, Wph);
    pack_xw   <<<4096,  256, 0, stream>>>(Wih, Xw);
    pack_bias <<<16,    256, 0, stream>>>(bih, bhh, bc);
    pack_wout <<<512,   256, 0, stream>>>(Wout, WoBf);
    pack_x    <<<130944,256, 0, stream>>>(seq, Xb);
    init_state<<<512,   256, 0, stream>>>(Hblk, bar);

    lstm_persist<<<WGS, 512, 0, stream>>>(Xb, Hblk, Wph, Xw, bc, bar);

    head_ls<<<dim3(8, T_STEPS), 256, 0, stream>>>(Hblk, WoBf, bout, out);
}